// Round 2
// baseline (144.027 us; speedup 1.0000x reference)
//
#include <hip/hip_runtime.h>
#include <hip/hip_bf16.h>

#define B_ 128
#define S_ 513
#define H_ 256
#define SH_ (S_ * H_)

typedef __attribute__((ext_vector_type(8))) short short8;
typedef __attribute__((ext_vector_type(4))) float f32x4;

// Pack 8 fp32 -> 8 bf16 (RNE) via the HW packed converter.
static __device__ inline short8 pack8(float4 a, float4 b) {
    union { short8 s; __hip_bfloat162 h[4]; } u;
    u.h[0] = __float22bfloat162_rn(make_float2(a.x, a.y));
    u.h[1] = __float22bfloat162_rn(make_float2(a.z, a.w));
    u.h[2] = __float22bfloat162_rn(make_float2(b.x, b.y));
    u.h[3] = __float22bfloat162_rn(make_float2(b.z, b.w));
    return u.s;
}

// Prep: W fp32 -> bf16 in fragment-major layout (m, kc, d, 8) so the main
// kernel's per-kk W fragment loads are coalesced (16 lanes -> 256 B run).
// Also bias sum (256 floats).
__global__ void prep_kernel(const float* __restrict__ W,
                            const float* __restrict__ bias,
                            unsigned short* __restrict__ Wbf,
                            float* __restrict__ bsum) {
    int t = blockIdx.x * 256 + threadIdx.x;
    if (t < 5 * 32 * 256) {                 // one thread per (m, d, kc)
        int m  = t >> 13;                   // t / 8192
        int r  = t & 8191;
        int d  = r >> 5;
        int kc = r & 31;                    // 8-elem k-chunk
        const float* src = W + (((size_t)m * 256 + d) * 256 + kc * 8);
        float4 v0 = *(const float4*)src;
        float4 v1 = *(const float4*)(src + 4);
        *(short8*)(Wbf + ((size_t)(m * 32 + kc) * 256 + d) * 8) = pack8(v0, v1);
    }
    if (t < H_) {
        float s = 0.f;
#pragma unroll
        for (int i = 0; i < 5; ++i) s += bias[i * H_ + t];
        bsum[t] = s;
    }
}

// Persistent per-s block: grid = 513, 256 threads (4 waves, one 64-wide
// d-slice each). Each block processes its s-position's full batch as 4
// quarter-tiles (M=32), software-pipelined across a 2x16KB LDS double
// buffer: loads for quarter q+1 stream while quarter q computes/stores.
// This de-lockstops the grid: with 513 independent pipelines, HBM sees a
// continuous read+write mix instead of grid-wide phase bursts.
template <int MODE>
__global__ __launch_bounds__(256, 2)
void sel_gemm_kernel(const float* __restrict__ x,
                     const void* __restrict__ Wp,
                     const void* __restrict__ bp,
                     float* __restrict__ out) {
    const int s     = blockIdx.x;           // 0..512
    const int m_idx = (s < 3) ? s : ((s & 1) ? 3 : 4);

    // Double buffer: 2 x (32 rows x 256 bf16) = 2 x 16 KB.
    // 16-B chunk c of row r stored at c ^ (r&7): fragment reads ~2-way (free).
    __shared__ unsigned short As[2][32 * 256];

    const int t    = threadIdx.x;
    const int lane = t & 63;
    const int w    = t >> 6;        // 0..3 : d-slice (w*64)
    const int lrow = lane & 15;
    const int quad = lane >> 4;
    const int c    = t & 31;        // this thread's 16-B chunk within a row
    const int rb   = t >> 5;        // row base 0..7

    const float* xs = x + (size_t)s * H_;

    float4 ld[4][2];                // staged quarter-tile (32 VGPRs)

    auto issue = [&](int q) {       // global loads for quarter q (no wait)
#pragma unroll
        for (int i = 0; i < 4; ++i) {
            const int r = i * 8 + rb;
            const float* src = xs + (size_t)(q * 32 + r) * SH_ + c * 8;
            ld[i][0] = *(const float4*)src;
            ld[i][1] = *(const float4*)(src + 4);
        }
    };
    auto commit = [&](int buf) {    // pack + swizzled LDS write
#pragma unroll
        for (int i = 0; i < 4; ++i) {
            const int r = i * 8 + rb;
            *(short8*)&As[buf][r * 256 + ((c ^ (r & 7)) * 8)] =
                pack8(ld[i][0], ld[i][1]);
        }
    };

    // ---- Bias (hoisted; 4 x f32x4 along this wave's d-slice).
    f32x4 bj4[4];
    if (MODE == 0) {
        const float* bsum = (const float*)bp;
#pragma unroll
        for (int j = 0; j < 4; ++j)
            bj4[j] = *(const f32x4*)(bsum + w * 64 + j * 16 + quad * 4);
    } else {
        const float* bias = (const float*)bp;
#pragma unroll
        for (int j = 0; j < 4; ++j) {
            const int d0 = w * 64 + j * 16 + quad * 4;
#pragma unroll
            for (int r = 0; r < 4; ++r) {
                float sum = 0.f;
#pragma unroll
                for (int i = 0; i < 5; ++i) sum += bias[i * H_ + d0 + r];
                bj4[j][r] = sum;
            }
        }
    }

    // ---- Prologue: stage quarter 0.
    issue(0);
    commit(0);

#pragma unroll
    for (int q = 0; q < 4; ++q) {
        const int cur = q & 1;
        __syncthreads();            // buf[cur] ready for all waves
        if (q < 3) issue(q + 1);    // prefetch next quarter (post-barrier so
                                    // the barrier's vmcnt drain can't eat it)

        f32x4 acc[2][4];
#pragma unroll
        for (int i = 0; i < 2; ++i)
#pragma unroll
            for (int j = 0; j < 4; ++j) {
                f32x4 z = {0.f, 0.f, 0.f, 0.f};
                acc[i][j] = z;
            }

        const unsigned short* Ab = As[cur];

        // K-loop: 8 steps of 32. W frags from L2 (640 KB total, hot).
#pragma unroll
        for (int kk = 0; kk < 8; ++kk) {
            short8 wfr[4];
            if (MODE == 0) {
                const unsigned short* Wk =
                    (const unsigned short*)Wp +
                    ((size_t)(m_idx * 32 + kk * 4 + quad) * 256) * 8;
#pragma unroll
                for (int j = 0; j < 4; ++j)
                    wfr[j] = *(const short8*)(Wk +
                              (size_t)(w * 64 + j * 16 + lrow) * 8);
            } else {
                const float* Wb = (const float*)Wp + (size_t)m_idx * H_ * H_;
#pragma unroll
                for (int j = 0; j < 4; ++j) {
                    const float* wrow = Wb +
                        (size_t)(w * 64 + j * 16 + lrow) * H_ + kk * 32 + quad * 8;
                    float4 v0 = *(const float4*)wrow;
                    float4 v1 = *(const float4*)(wrow + 4);
                    wfr[j] = pack8(v0, v1);
                }
            }

            short8 xfr[2];
            const int cc = kk * 4 + quad;
#pragma unroll
            for (int i = 0; i < 2; ++i) {
                const int r = i * 16 + lrow;
                xfr[i] = *(const short8*)&Ab[r * 256 + ((cc ^ (r & 7)) * 8)];
            }

#pragma unroll
            for (int j = 0; j < 4; ++j)
#pragma unroll
                for (int i = 0; i < 2; ++i)
                    acc[i][j] = __builtin_amdgcn_mfma_f32_16x16x32_bf16(
                        wfr[j], xfr[i], acc[i][j], 0, 0, 0);
        }

        // ---- Epilogue. A=W, B=x -> col(lane&15)=batch, row(quad*4+reg)=d.
#pragma unroll
        for (int j = 0; j < 4; ++j) {
            const int d0 = w * 64 + j * 16 + quad * 4;
#pragma unroll
            for (int i = 0; i < 2; ++i) {
                const int b = q * 32 + i * 16 + lrow;
                f32x4 v = acc[i][j] + bj4[j];
                *(f32x4*)(out + ((size_t)b * S_ + s) * H_ + d0) = v;
            }
        }

        // ---- Land the prefetch into the other buffer (waits its loads).
        if (q < 3) commit(cur ^ 1);
    }
}

extern "C" void kernel_launch(void* const* d_in, const int* in_sizes, int n_in,
                              void* d_out, int out_size, void* d_ws, size_t ws_size,
                              hipStream_t stream) {
    const float* x    = (const float*)d_in[0];
    const float* W    = (const float*)d_in[1];
    const float* bias = (const float*)d_in[2];
    float* out = (float*)d_out;

    const size_t w_elems  = (size_t)5 * H_ * H_;
    const size_t ws_need  = w_elems * sizeof(unsigned short) + H_ * sizeof(float);

    if (ws_size >= ws_need) {
        unsigned short* Wbf = (unsigned short*)d_ws;
        float* bsum = (float*)((char*)d_ws + w_elems * sizeof(unsigned short));
        prep_kernel<<<dim3(160), dim3(256), 0, stream>>>(W, bias, Wbf, bsum);
        sel_gemm_kernel<0><<<dim3(S_), dim3(256), 0, stream>>>(
            x, (const void*)Wbf, (const void*)bsum, out);
    } else {
        sel_gemm_kernel<1><<<dim3(S_), dim3(256), 0, stream>>>(
            x, (const void*)W, (const void*)bias, out);
    }
}

// Round 3
// 134.669 us; speedup vs baseline: 1.0695x; 1.0695x over previous
//
#include <hip/hip_runtime.h>
#include <hip/hip_bf16.h>

#define B_ 128
#define S_ 513
#define H_ 256
#define SH_ (S_ * H_)

typedef __attribute__((ext_vector_type(8))) short short8;
typedef __attribute__((ext_vector_type(4))) float f32x4;

// Pack 8 fp32 -> 8 bf16 (RNE) via the HW packed converter.
static __device__ inline short8 pack8(float4 a, float4 b) {
    union { short8 s; __hip_bfloat162 h[4]; } u;
    u.h[0] = __float22bfloat162_rn(make_float2(a.x, a.y));
    u.h[1] = __float22bfloat162_rn(make_float2(a.z, a.w));
    u.h[2] = __float22bfloat162_rn(make_float2(b.x, b.y));
    u.h[3] = __float22bfloat162_rn(make_float2(b.z, b.w));
    return u.s;
}

// Prep: W fp32 -> bf16 in fragment-major layout (m, kc, d, 8) so the main
// kernel's per-kk W fragment loads are coalesced (16 lanes -> 256 B run).
// Also bias sum (256 floats).
__global__ void prep_kernel(const float* __restrict__ W,
                            const float* __restrict__ bias,
                            unsigned short* __restrict__ Wbf,
                            float* __restrict__ bsum) {
    int t = blockIdx.x * 256 + threadIdx.x;
    if (t < 5 * 32 * 256) {                 // one thread per (m, d, kc)
        int m  = t >> 13;                   // t / 8192
        int r  = t & 8191;
        int d  = r >> 5;
        int kc = r & 31;                    // 8-elem k-chunk
        const float* src = W + (((size_t)m * 256 + d) * 256 + kc * 8);
        float4 v0 = *(const float4*)src;
        float4 v1 = *(const float4*)(src + 4);
        *(short8*)(Wbf + ((size_t)(m * 32 + kc) * 256 + d) * 8) = pack8(v0, v1);
    }
    if (t < H_) {
        float s = 0.f;
#pragma unroll
        for (int i = 0; i < 5; ++i) s += bias[i * H_ + t];
        bsum[t] = s;
    }
}

// One block = one (s, batch-quarter): M=32, N=256, K=256.
// 256 threads = 4 waves, each owning a 32(b) x 64(d) tile via 2x4 MFMA frags.
// Round-1 structure (stage -> one barrier -> compute -> store) -- the
// persistent-pipeline variant (round 2) REGRESSED: block-level concurrency,
// not intra-block pipelining, is what feeds HBM here.
// Budget: 32 AGPR acc + ~50 VGPR -> launch_bounds(256,6) => 6 blocks/CU
// (24 waves/CU, 96 KB LDS), grid 2052 => continuous block turnover; six
// phase-offset streams/CU keep reads, L2 W-loads, MFMA and writes mixed.
template <int MODE>
__global__ __launch_bounds__(256, 6)
void sel_gemm_kernel(const float* __restrict__ x,
                     const void* __restrict__ Wp,
                     const void* __restrict__ bp,
                     float* __restrict__ out) {
    const int s     = blockIdx.x >> 2;      // 0..512
    const int qtr   = blockIdx.x & 3;       // batch quarter: rows qtr*32 ..
    const int m_idx = (s < 3) ? s : ((s & 1) ? 3 : 4);

    // 32 rows x 256 bf16 = 16 KB. 16-B chunk c of row r stored at c ^ (r&7):
    // fragment reads land 2 lanes/16B-slot (free); staging writes stay
    // conflict-free (XOR permutes within 128-B stripes).
    __shared__ unsigned short As[32 * 256];

    const int t    = threadIdx.x;
    const int lane = t & 63;
    const int w    = t >> 6;        // 0..3 : d-slice (w*64)
    const int lrow = lane & 15;
    const int quad = lane >> 4;

    // ---- Stage x: 32 rows x 256 fp32 -> bf16 LDS, swizzled. 4 chunks/thr.
    const float* xs = x + (size_t)s * H_ + (size_t)qtr * 32 * SH_;
#pragma unroll
    for (int i = 0; i < 4; ++i) {
        int flat = i * 256 + t;
        int r = flat >> 5;              // 0..31 (batch row within quarter)
        int c = flat & 31;              // 16-B chunk (8 bf16) within row
        const float* src = xs + (size_t)r * SH_ + c * 8;
        float4 v0 = *(const float4*)src;
        float4 v1 = *(const float4*)(src + 4);
        *(short8*)&As[r * 256 + ((c ^ (r & 7)) * 8)] = pack8(v0, v1);
    }

    f32x4 acc[2][4];
#pragma unroll
    for (int i = 0; i < 2; ++i)
#pragma unroll
        for (int j = 0; j < 4; ++j) {
            f32x4 z = {0.f, 0.f, 0.f, 0.f};
            acc[i][j] = z;
        }

    __syncthreads();   // the only barrier

    // ---- K-loop: 8 steps of 32. W frags from L2 (640 KB total, hot).
    // wfr loaded per-j to keep live VGPRs low (occupancy > ILP here; TLP
    // from 24 waves/CU hides the L2 latency).
#pragma unroll
    for (int kk = 0; kk < 8; ++kk) {
        short8 xfr[2];
        const int cc = kk * 4 + quad;   // chunk column of this lane's frag
#pragma unroll
        for (int i = 0; i < 2; ++i) {
            const int r = i * 16 + lrow;
            xfr[i] = *(const short8*)&As[r * 256 + ((cc ^ (r & 7)) * 8)];
        }

#pragma unroll
        for (int j = 0; j < 4; ++j) {
            short8 wfr;
            if (MODE == 0) {
                // layout (m, kc, d, 8): lane reads d = w*64 + j*16 + lrow,
                // kc = kk*4 + quad -> 16 lanes = 256 B contiguous.
                const unsigned short* Wk =
                    (const unsigned short*)Wp +
                    ((size_t)(m_idx * 32 + kk * 4 + quad) * 256) * 8;
                wfr = *(const short8*)(Wk + (size_t)(w * 64 + j * 16 + lrow) * 8);
            } else {
                const float* Wb = (const float*)Wp + (size_t)m_idx * H_ * H_;
                const float* wrow = Wb + (size_t)(w * 64 + j * 16 + lrow) * H_
                                    + kk * 32 + quad * 8;
                float4 v0 = *(const float4*)wrow;
                float4 v1 = *(const float4*)(wrow + 4);
                wfr = pack8(v0, v1);
            }
#pragma unroll
            for (int i = 0; i < 2; ++i)
                acc[i][j] = __builtin_amdgcn_mfma_f32_16x16x32_bf16(
                    wfr, xfr[i], acc[i][j], 0, 0, 0);
        }
    }

    // ---- Epilogue. A=W, B=x -> col(lane&15)=batch, row(quad*4+reg)=d.
    // Per (i,j): one float4 store along d. 8 stores/lane total.
#pragma unroll
    for (int j = 0; j < 4; ++j) {
        const int d0 = w * 64 + j * 16 + quad * 4;
        f32x4 bj;
        if (MODE == 0) {
            bj = *(const f32x4*)((const float*)bp + d0);
        } else {
            const float* bias = (const float*)bp;
#pragma unroll
            for (int r = 0; r < 4; ++r) {
                float sum = 0.f;
#pragma unroll
                for (int i = 0; i < 5; ++i) sum += bias[i * H_ + d0 + r];
                bj[r] = sum;
            }
        }
#pragma unroll
        for (int i = 0; i < 2; ++i) {
            const int b = qtr * 32 + i * 16 + lrow;
            f32x4 v = acc[i][j] + bj;
            *(f32x4*)(out + ((size_t)b * S_ + s) * H_ + d0) = v;
        }
    }
}

extern "C" void kernel_launch(void* const* d_in, const int* in_sizes, int n_in,
                              void* d_out, int out_size, void* d_ws, size_t ws_size,
                              hipStream_t stream) {
    const float* x    = (const float*)d_in[0];
    const float* W    = (const float*)d_in[1];
    const float* bias = (const float*)d_in[2];
    float* out = (float*)d_out;

    const size_t w_elems  = (size_t)5 * H_ * H_;
    const size_t ws_need  = w_elems * sizeof(unsigned short) + H_ * sizeof(float);

    if (ws_size >= ws_need) {
        unsigned short* Wbf = (unsigned short*)d_ws;
        float* bsum = (float*)((char*)d_ws + w_elems * sizeof(unsigned short));
        prep_kernel<<<dim3(160), dim3(256), 0, stream>>>(W, bias, Wbf, bsum);
        sel_gemm_kernel<0><<<dim3(4 * S_), dim3(256), 0, stream>>>(
            x, (const void*)Wbf, (const void*)bsum, out);
    } else {
        sel_gemm_kernel<1><<<dim3(4 * S_), dim3(256), 0, stream>>>(
            x, (const void*)W, (const void*)bias, out);
    }
}